// Round 2
// baseline (392.675 us; speedup 1.0000x reference)
//
#include <hip/hip_runtime.h>
#include <hip/hip_bf16.h>

// Problem constants (B=2, L=2048, Dm=768, di=1536, ds=16, dc=4)
#define BB 2
#define LL 2048
#define DM 768
#define DI 1536
#define DS 16
#define MM (BB*LL)   // 4096 rows
#define NCH 64       // scan chunks
#define CHL 32       // steps per chunk
#define SEQS (BB*DI*DS)  // 49152 independent scalar recurrences
#define NC2 1664     // delta GEMM fused N: 1536 (W_dt) + 32 (W_x) + 96 pad

typedef __hip_bfloat16 bf16;
typedef short bf16x8 __attribute__((ext_vector_type(8)));
typedef float f32x4  __attribute__((ext_vector_type(4)));

__device__ __forceinline__ void gl_lds16(const void* g, void* l) {
  __builtin_amdgcn_global_load_lds((const __attribute__((address_space(1))) void*)g,
                                   (__attribute__((address_space(3))) void*)l, 16, 0, 0);
}

// ---------------- merged prep: x/W_in/W_out -> bf16, build Wcomb ----------------
struct bf4 { __hip_bfloat16 a, b, c, d; };
#define PR0 786432                   // x: 4096*768/4
#define PR1 589824                   // W_in: 3072*768/4
#define PR2 294912                   // W_out: 768*1536/4
#define PR3 638976                   // Wcomb: 1664*1536/4
#define PRTOT (PR0+PR1+PR2+PR3)      // 2310144

__global__ __launch_bounds__(256) void prep_k(const float* __restrict__ x,
                                              const float* __restrict__ Win,
                                              const float* __restrict__ Wout,
                                              const float* __restrict__ Wdt,
                                              const float* __restrict__ Wx,
                                              __hip_bfloat16* __restrict__ xbf,
                                              __hip_bfloat16* __restrict__ Winbf,
                                              __hip_bfloat16* __restrict__ Woutbf,
                                              __hip_bfloat16* __restrict__ Wcomb) {
  int i = blockIdx.x * 256 + threadIdx.x;
  if (i >= PRTOT) return;
  float4 v; __hip_bfloat16* dst; int di_;
  if (i < PR0)                    { v = ((const float4*)x)[i];                 dst = xbf;    di_ = i; }
  else if (i < PR0 + PR1)         { di_ = i - PR0; v = ((const float4*)Win)[di_];  dst = Winbf; }
  else if (i < PR0 + PR1 + PR2)   { di_ = i - PR0 - PR1; v = ((const float4*)Wout)[di_]; dst = Woutbf; }
  else {
    di_ = i - PR0 - PR1 - PR2;    // Wcomb = [W_dt ; W_x ; 0-pad]
    int e = di_ * 4, row = e / DI, colb = e % DI;
    if (row < DI)            v = ((const float4*)Wdt)[di_];
    else if (row < DI + 32)  v = *(const float4*)(Wx + (size_t)(row - DI) * DI + colb);
    else                     v = make_float4(0.f, 0.f, 0.f, 0.f);
    dst = Wcomb;
  }
  bf4 o = { __float2bfloat16(v.x), __float2bfloat16(v.y),
            __float2bfloat16(v.z), __float2bfloat16(v.w) };
  ((bf4*)dst)[di_] = o;
}

// ---------------- R5 pipelined LDS-staged GEMM ----------------
// C[M,N] = A[M,K_sub] * W[N,K_sub]^T. BM template param (128 or 256), BN=128.
// 256 threads = 4 waves (2x2), wave tile (BM/2)x64, 3 LDS buffers, 2 tiles in
// flight, counted vmcnt(NPW)+barrier per iter.
// Intensity: BM*128/(BM+128) FLOP per staged byte -> 64 (BM=128), 85 (BM=256).
// EPI: 5 = split bf16: col<DI -> C (stride DI), else -> C2 (stride DI) [xz GEMM]
//      6 = col<DI -> bf16(softplus(v+bias[col])) -> C (stride DI);
//          col in [DI,DI+32) -> fp32 C2 (stride 32); else discard   [delta+xdbl]
//      7 = fp32 partial store at C + blockIdx.z*M*N                 [split-K]
template<int EPI, int BM>
__global__ __launch_bounds__(256) void gemm_db(const bf16* __restrict__ A,
                                               const bf16* __restrict__ W,
                                               void* __restrict__ Cv,
                                               void* __restrict__ C2v,
                                               const float* __restrict__ bias,
                                               int M, int N, int K, int Kstride) {
  constexpr int NA  = BM / 64;
  constexpr int NPW = NA + 2;
  __shared__ short sA[3][BM * 32];
  __shared__ short sB[3][128 * 32];
  const int t = threadIdx.x;
  const int m0 = blockIdx.y * BM, n0 = blockIdx.x * 128;
  const size_t koff = (size_t)blockIdx.z * K;
  const int w = t >> 6, lane = t & 63;
  const int wm = (w >> 1) * (BM / 2), wn = (w & 1) * 64;
  const int ga = wm >> 4, gb = wn >> 4;

  f32x4 acc[BM / 32][4] = {};

  const int srow = lane & 15, skoff = (lane >> 4) * 8;
  const bf16* gA[NA]; const bf16* gB[2];
  #pragma unroll
  for (int j = 0; j < NA; j++)
    gA[j] = A + (size_t)(m0 + (w + 4 * j) * 16 + srow) * Kstride + koff + skoff;
  #pragma unroll
  for (int j = 0; j < 2; j++)
    gB[j] = W + (size_t)(n0 + (w + 4 * j) * 16 + srow) * Kstride + koff + skoff;

  #define ISSUE(buf, k0)                                              \
    do {                                                              \
      _Pragma("unroll")                                               \
      for (int j = 0; j < NA; j++)                                    \
        gl_lds16(gA[j] + (k0), &sA[buf][(w + 4 * j) * 512]);          \
      _Pragma("unroll")                                               \
      for (int j = 0; j < 2; j++)                                     \
        gl_lds16(gB[j] + (k0), &sB[buf][(w + 4 * j) * 512]);          \
    } while (0)

  ISSUE(0, 0);
  ISSUE(1, 32);
  int p = 0;
  for (int k0 = 0; k0 < K; k0 += 32) {
    if (k0 + 32 < K) {
      asm volatile("s_waitcnt vmcnt(%0)\n\ts_barrier" :: "n"(NPW) : "memory");
    } else {
      asm volatile("s_waitcnt vmcnt(0)\n\ts_barrier" ::: "memory");
    }
    if (k0 + 64 < K) {
      int nb = p + 2; if (nb >= 3) nb -= 3;
      ISSUE(nb, k0 + 64);
    }
    const bf16x8* fA = (const bf16x8*)sA[p];
    const bf16x8* fB = (const bf16x8*)sB[p];
    bf16x8 af[BM / 32], bfr[4];
    #pragma unroll
    for (int i = 0; i < BM / 32; i++) af[i]  = fA[(ga + i) * 64 + lane];
    #pragma unroll
    for (int j = 0; j < 4; j++)       bfr[j] = fB[(gb + j) * 64 + lane];
    #pragma unroll
    for (int i = 0; i < BM / 32; i++)
      #pragma unroll
      for (int j = 0; j < 4; j++)
        acc[i][j] = __builtin_amdgcn_mfma_f32_16x16x32_bf16(af[i], bfr[j], acc[i][j], 0, 0, 0);
    p++; if (p >= 3) p = 0;
  }
  #undef ISSUE

  const int q = lane >> 4, mm = lane & 15;
  #pragma unroll
  for (int i = 0; i < BM / 32; i++)
    #pragma unroll
    for (int j = 0; j < 4; j++) {
      int r0  = m0 + wm + i * 16 + q * 4;
      int col = n0 + wn + j * 16 + mm;
      #pragma unroll
      for (int r = 0; r < 4; r++) {
        float v = acc[i][j][r];
        if (EPI == 5) {
          if (col < DI) ((bf16*)Cv) [(size_t)(r0 + r) * DI + col]        = __float2bfloat16(v);
          else          ((bf16*)C2v)[(size_t)(r0 + r) * DI + (col - DI)] = __float2bfloat16(v);
        } else if (EPI == 6) {
          if (col < DI) {
            float vv = v + bias[col];
            vv = (vv > 15.f) ? vv : __logf(1.f + __expf(vv));
            ((bf16*)Cv)[(size_t)(r0 + r) * DI + col] = __float2bfloat16(vv);
          } else if (col < DI + 32) {
            ((float*)C2v)[(size_t)(r0 + r) * 32 + (col - DI)] = v;
          }
        } else {  // EPI == 7: split-K partial
          ((float*)Cv)[(size_t)blockIdx.z * M * N + (size_t)(r0 + r) * N + col] = v;
        }
      }
    }
}

// ---------------- split-K reduce: out = P0 + P1 (fp32, float4) ----------------
__global__ __launch_bounds__(256) void redk_k(const float4* __restrict__ P,
                                              float4* __restrict__ out, int n4) {
  int i = blockIdx.x * 256 + threadIdx.x;
  if (i >= n4) return;
  float4 a = P[i], b = P[i + n4];
  out[i] = make_float4(a.x + b.x, a.y + b.y, a.z + b.z, a.w + b.w);
}

// ---------------- depthwise causal conv (dc=4) + SiLU; bf16 in/out ----------------
__global__ __launch_bounds__(256) void conv_silu_k(const bf16* __restrict__ xpart,
                                                   const float* __restrict__ Wc,
                                                   __hip_bfloat16* __restrict__ xcbf) {
  int idx = blockIdx.x * 256 + threadIdx.x;
  if (idx >= MM * DI) return;
  int d = idx % DI;
  int r = idx / DI;
  int l = r & (LL - 1);
  float4 wv = ((const float4*)Wc)[d];  // W_conv[d, 0, 0..3]
  const bf16* xp = xpart + (size_t)r * DI + d;
  float acc = wv.w * __bfloat162float(xp[0]);
  if (l >= 1) acc += wv.z * __bfloat162float(xp[-(ptrdiff_t)DI]);
  if (l >= 2) acc += wv.y * __bfloat162float(xp[-(ptrdiff_t)(2 * DI)]);
  if (l >= 3) acc += wv.x * __bfloat162float(xp[-(ptrdiff_t)(3 * DI)]);
  float s = acc / (1.f + __expf(-acc));   // silu
  xcbf[idx] = __float2bfloat16(s);
}

// ================= chunked selective scan (NCH=64, CHL=32) =================
__global__ __launch_bounds__(64) void scan_part_k(const bf16* __restrict__ delta,
                                                  const float* __restrict__ xdbl,
                                                  const float* __restrict__ A_log,
                                                  float* __restrict__ prodA,
                                                  float* __restrict__ hend) {
  __shared__ float sBC[CHL * 32];
  const int t = threadIdx.x;
  const int dg = blockIdx.x % (DI / 64);
  const int chunk = (blockIdx.x / (DI / 64)) % NCH;
  const int b = blockIdx.x / ((DI / 64) * NCH);
  const int d = dg * 64 + t;

  float a[16];
  #pragma unroll
  for (int s = 0; s < 16; s++) a[s] = -__expf(A_log[s]);

  const float4* src = (const float4*)(xdbl + ((size_t)b * LL + chunk * CHL) * 32);
  #pragma unroll
  for (int k = 0; k < CHL * 32 / 4 / 64; k++) ((float4*)sBC)[t + k * 64] = src[t + k * 64];
  __syncthreads();

  float h[16], p[16];
  #pragma unroll
  for (int s = 0; s < 16; s++) { h[s] = 0.f; p[s] = 1.f; }

  const bf16* dptr = delta + ((size_t)b * LL + chunk * CHL) * DI + d;
  #pragma unroll 2
  for (int i = 0; i < CHL; i++) {
    float dlt = __bfloat162float(dptr[(size_t)i * DI]);
    const float4* bc = (const float4*)(sBC + i * 32);
    float4 B0 = bc[0], B1 = bc[1], B2 = bc[2], B3 = bc[3];
    float Bv[16] = {B0.x,B0.y,B0.z,B0.w, B1.x,B1.y,B1.z,B1.w,
                    B2.x,B2.y,B2.z,B2.w, B3.x,B3.y,B3.z,B3.w};
    #pragma unroll
    for (int s = 0; s < 16; s++) {
      float dA = __expf(dlt * a[s]);
      h[s] = dA * h[s] + dlt * Bv[s];
      p[s] *= dA;
    }
  }
  size_t o = (size_t)chunk * SEQS + ((size_t)b * DI + d) * 16;
  #pragma unroll
  for (int s = 0; s < 16; s += 4) {
    ((float4*)(prodA + o))[s >> 2] = make_float4(p[s], p[s+1], p[s+2], p[s+3]);
    ((float4*)(hend  + o))[s >> 2] = make_float4(h[s], h[s+1], h[s+2], h[s+3]);
  }
}

__global__ __launch_bounds__(64) void scan_comb_k(const float* __restrict__ prodA,
                                                  const float* __restrict__ hend,
                                                  float* __restrict__ hstart) {
  int idx = blockIdx.x * 64 + threadIdx.x;   // 0 .. SEQS-1
  float run = 0.f;
  #pragma unroll 4
  for (int c = 0; c < NCH; c++) {
    size_t o = (size_t)c * SEQS + idx;
    hstart[o] = run;
    run = prodA[o] * run + hend[o];
  }
}

__global__ __launch_bounds__(64) void scan_fin_k(const bf16* __restrict__ delta,
                                                 const float* __restrict__ xdbl,
                                                 const float* __restrict__ A_log,
                                                 const float* __restrict__ Dp,
                                                 const bf16* __restrict__ xcbf,
                                                 const bf16* __restrict__ zbf,
                                                 const float* __restrict__ hstart,
                                                 __hip_bfloat16* __restrict__ ypbf) {
  __shared__ float sBC[CHL * 32];
  const int t = threadIdx.x;
  const int dg = blockIdx.x % (DI / 64);
  const int chunk = (blockIdx.x / (DI / 64)) % NCH;
  const int b = blockIdx.x / ((DI / 64) * NCH);
  const int d = dg * 64 + t;

  float a[16];
  #pragma unroll
  for (int s = 0; s < 16; s++) a[s] = -__expf(A_log[s]);

  const float4* src = (const float4*)(xdbl + ((size_t)b * LL + chunk * CHL) * 32);
  #pragma unroll
  for (int k = 0; k < CHL * 32 / 4 / 64; k++) ((float4*)sBC)[t + k * 64] = src[t + k * 64];
  __syncthreads();

  float h[16];
  size_t o = (size_t)chunk * SEQS + ((size_t)b * DI + d) * 16;
  #pragma unroll
  for (int s = 0; s < 16; s += 4) {
    float4 v = ((const float4*)(hstart + o))[s >> 2];
    h[s] = v.x; h[s+1] = v.y; h[s+2] = v.z; h[s+3] = v.w;
  }
  const float Dv = Dp[d];

  const size_t rbase = (size_t)b * LL + chunk * CHL;
  const bf16* dptr = delta + rbase * DI + d;
  const bf16* xcp  = xcbf  + rbase * DI + d;
  const bf16* zp   = zbf   + rbase * DI + d;
  __hip_bfloat16* yp = ypbf + rbase * DI + d;

  #pragma unroll 2
  for (int i = 0; i < CHL; i++) {
    float dlt = __bfloat162float(dptr[(size_t)i * DI]);
    const float4* bc = (const float4*)(sBC + i * 32);
    float4 B0 = bc[0], B1 = bc[1], B2 = bc[2], B3 = bc[3];
    float4 C0 = bc[4], C1 = bc[5], C2 = bc[6], C3 = bc[7];
    float Bv[16] = {B0.x,B0.y,B0.z,B0.w, B1.x,B1.y,B1.z,B1.w,
                    B2.x,B2.y,B2.z,B2.w, B3.x,B3.y,B3.z,B3.w};
    float Cv[16] = {C0.x,C0.y,C0.z,C0.w, C1.x,C1.y,C1.z,C1.w,
                    C2.x,C2.y,C2.z,C2.w, C3.x,C3.y,C3.z,C3.w};
    float y = 0.f;
    #pragma unroll
    for (int s = 0; s < 16; s++) {
      float dA = __expf(dlt * a[s]);
      h[s] = dA * h[s] + dlt * Bv[s];
      y += h[s] * Cv[s];
    }
    float xcv = __bfloat162float(xcp[(size_t)i * DI]);
    float zv  = __bfloat162float(zp [(size_t)i * DI]);
    float val = (y + Dv * xcv) * (zv / (1.f + __expf(-zv)));
    yp[(size_t)i * DI] = __float2bfloat16(val);
  }
}

extern "C" void kernel_launch(void* const* d_in, const int* in_sizes, int n_in,
                              void* d_out, int out_size, void* d_ws, size_t ws_size,
                              hipStream_t stream) {
  const float* x      = (const float*)d_in[0];
  const float* W_in   = (const float*)d_in[1];
  const float* W_conv = (const float*)d_in[2];
  const float* W_x    = (const float*)d_in[3];
  const float* W_dt   = (const float*)d_in[4];
  const float* b_dt   = (const float*)d_in[5];
  const float* A_log  = (const float*)d_in[6];
  const float* Dp     = (const float*)d_in[7];
  const float* W_out  = (const float*)d_in[8];
  float* out = (float*)d_out;

  char* ws = (char*)d_ws;
  // workspace layout (bytes), max used = 119668736
  bf16*  xpartbf = (bf16*)(ws + 0);          // 12582912 (dead after conv)
  bf16*  zbf     = (bf16*)(ws + 12582912);   // 12582912 (dead after scan_fin)
  bf16*  xbf     = (bf16*)(ws + 25165824);   //  6291456 (dead after GEMM1)
  bf16*  Winbf   = (bf16*)(ws + 31457280);   //  4718592 (dead after GEMM1)
  bf16*  xcbf    = (bf16*)(ws + 36175872);   // 12582912
  bf16*  Wcomb   = (bf16*)(ws + 48758784);   //  5111808
  bf16*  deltabf = (bf16*)(ws + 53870592);   // 12582912
  float* xdbl    = (float*)(ws + 66453504);  //   524288
  bf16*  ypbf    = (bf16*)(ws + 66977792);   // 12582912
  bf16*  Woutbf  = (bf16*)(ws + 79560704);   //  2359296
  float* prodA   = (float*)(ws + 81920000);  // 64*49152*4 = 12582912
  float* hend    = (float*)(ws + 94502912);  // 12582912
  float* hstart  = (float*)(ws + 107085824); // 12582912
  // GEMM3 split-K partials alias [0, 25165824) (xpartbf+zbf, both dead by then):
  float* P3      = (float*)(ws + 0);         // 2 * 4096*768*4 = 25165824

  // merged prep: bf16 converts + Wcomb build
  prep_k<<<(PRTOT + 255) / 256, 256, 0, stream>>>(x, W_in, W_out, W_dt, W_x,
                                                  xbf, Winbf, Woutbf, Wcomb);

  // xz = x @ W_in.T (4096 x 3072, K=768), BM=256 tiles (85 FLOP/staged-byte),
  // split bf16 stores into xpartbf | zbf
  {
    dim3 g(3072 / 128, 4096 / 256, 1);   // 384 blocks
    gemm_db<5, 256><<<g, 256, 0, stream>>>(xbf, Winbf, xpartbf, zbf, nullptr,
                                           MM, 2 * DI, DM, DM);
  }
  // xc = silu(causal_dwconv(xpart)), bf16
  conv_silu_k<<<(MM * DI + 255) / 256, 256, 0, stream>>>(xpartbf, W_conv, xcbf);
  // delta = bf16(softplus(xc @ W_dt.T + b_dt)) AND xdbl = xc @ W_x.T (fp32)
  // BM=256 tiles, unsplit K (split-K=2 was measured neutral on the GEMM and
  // cost +13us reduce: staged-BW-bound, not occupancy-bound)
  {
    dim3 g(NC2 / 128, 4096 / 256, 1);    // 208 blocks
    gemm_db<6, 256><<<g, 256, 0, stream>>>(xcbf, Wcomb, deltabf, xdbl, b_dt,
                                           MM, NC2, DI, DI);
  }
  // chunked selective scan + gating (NCH=64 -> 3072 blocks, 12 waves/CU)
  scan_part_k<<<BB * NCH * (DI / 64), 64, 0, stream>>>(deltabf, xdbl, A_log, prodA, hend);
  scan_comb_k<<<SEQS / 64, 64, 0, stream>>>(prodA, hend, hstart);
  scan_fin_k<<<BB * NCH * (DI / 64), 64, 0, stream>>>(deltabf, xdbl, A_log, Dp, xcbf, zbf,
                                                      hstart, ypbf);
  // out = y @ W_out.T (4096 x 768, K=1536): split-K=2, BM=128 (N too narrow
  // for 256-tiles), partials + reduce
  {
    dim3 g(768 / 128, 4096 / 128, 2);
    gemm_db<7, 128><<<g, 256, 0, stream>>>(ypbf, Woutbf, P3, nullptr, nullptr,
                                           MM, DM, DI / 2, DI);
  }
  redk_k<<<(786432 + 255) / 256, 256, 0, stream>>>((const float4*)P3, (float4*)out, 786432);
}

// Round 4
// 347.434 us; speedup vs baseline: 1.1302x; 1.1302x over previous
//
#include <hip/hip_runtime.h>
#include <hip/hip_bf16.h>

// Problem constants (B=2, L=2048, Dm=768, di=1536, ds=16, dc=4)
#define BB 2
#define LL 2048
#define DM 768
#define DI 1536
#define DS 16
#define MM (BB*LL)   // 4096 rows
#define NCH 64       // scan chunks
#define CHL 32       // steps per chunk
#define SEQS (BB*DI*DS)  // 49152 independent scalar recurrences
#define NC2 1664     // delta GEMM fused N: 1536 (W_dt) + 32 (W_x) + 96 pad

typedef __hip_bfloat16 bf16;
typedef short bf16x8 __attribute__((ext_vector_type(8)));
typedef float f32x4  __attribute__((ext_vector_type(4)));

__device__ __forceinline__ void gl_lds16(const void* g, void* l) {
  __builtin_amdgcn_global_load_lds((const __attribute__((address_space(1))) void*)g,
                                   (__attribute__((address_space(3))) void*)l, 16, 0, 0);
}

// ---------------- merged prep: x/W_in/W_out -> bf16, build Wcomb ----------------
struct bf4 { __hip_bfloat16 a, b, c, d; };
#define PR0 786432                   // x: 4096*768/4
#define PR1 589824                   // W_in: 3072*768/4
#define PR2 294912                   // W_out: 768*1536/4
#define PR3 638976                   // Wcomb: 1664*1536/4
#define PRTOT (PR0+PR1+PR2+PR3)      // 2310144

__global__ __launch_bounds__(256) void prep_k(const float* __restrict__ x,
                                              const float* __restrict__ Win,
                                              const float* __restrict__ Wout,
                                              const float* __restrict__ Wdt,
                                              const float* __restrict__ Wx,
                                              __hip_bfloat16* __restrict__ xbf,
                                              __hip_bfloat16* __restrict__ Winbf,
                                              __hip_bfloat16* __restrict__ Woutbf,
                                              __hip_bfloat16* __restrict__ Wcomb) {
  int i = blockIdx.x * 256 + threadIdx.x;
  if (i >= PRTOT) return;
  float4 v; __hip_bfloat16* dst; int di_;
  if (i < PR0)                    { v = ((const float4*)x)[i];                 dst = xbf;    di_ = i; }
  else if (i < PR0 + PR1)         { di_ = i - PR0; v = ((const float4*)Win)[di_];  dst = Winbf; }
  else if (i < PR0 + PR1 + PR2)   { di_ = i - PR0 - PR1; v = ((const float4*)Wout)[di_]; dst = Woutbf; }
  else {
    di_ = i - PR0 - PR1 - PR2;    // Wcomb = [W_dt ; W_x ; 0-pad]
    int e = di_ * 4, row = e / DI, colb = e % DI;
    if (row < DI)            v = ((const float4*)Wdt)[di_];
    else if (row < DI + 32)  v = *(const float4*)(Wx + (size_t)(row - DI) * DI + colb);
    else                     v = make_float4(0.f, 0.f, 0.f, 0.f);
    dst = Wcomb;
  }
  bf4 o = { __float2bfloat16(v.x), __float2bfloat16(v.y),
            __float2bfloat16(v.z), __float2bfloat16(v.w) };
  ((bf4*)dst)[di_] = o;
}

// ---------------- pipelined LDS-staged GEMM, depth-3 prefetch ----------------
// C[M,N] = A[M,K_sub] * W[N,K_sub]^T. BM=128, BN=128. 256 threads = 4 waves
// (2x2), wave tile 64x64. 4 LDS buffers, 3 tiles in flight (was 2 — r0-r2
// evidence: per-block K-iter is latency-bound; deeper counted-vmcnt pipeline
// raises tolerance 1.5x; LDS 64KB -> 2 blocks/CU, measured neutral vs 3).
// EPI: 5 = split bf16: col<DI -> C (stride DI), else -> C2 (stride DI) [xz GEMM]
//      6 = col<DI -> bf16(softplus(v+bias[col])) -> C (stride DI);
//          col in [DI,DI+32) -> fp32 C2 (stride 32); else discard   [delta+xdbl]
//      7 = fp32 partial store at C + blockIdx.z*M*N                 [split-K]
template<int EPI, int BM>
__global__ __launch_bounds__(256) void gemm_db(const bf16* __restrict__ A,
                                               const bf16* __restrict__ W,
                                               void* __restrict__ Cv,
                                               void* __restrict__ C2v,
                                               const float* __restrict__ bias,
                                               int M, int N, int K, int Kstride) {
  constexpr int NA  = BM / 64;
  constexpr int LPT = NA + 2;     // gl_lds16 per thread per tile
  __shared__ short sA[4][BM * 32];
  __shared__ short sB[4][128 * 32];
  const int t = threadIdx.x;
  const int m0 = blockIdx.y * BM, n0 = blockIdx.x * 128;
  const size_t koff = (size_t)blockIdx.z * K;
  const int w = t >> 6, lane = t & 63;
  const int wm = (w >> 1) * (BM / 2), wn = (w & 1) * 64;
  const int ga = wm >> 4, gb = wn >> 4;

  f32x4 acc[BM / 32][4] = {};

  const int srow = lane & 15, skoff = (lane >> 4) * 8;
  const bf16* gA[NA]; const bf16* gB[2];
  #pragma unroll
  for (int j = 0; j < NA; j++)
    gA[j] = A + (size_t)(m0 + (w + 4 * j) * 16 + srow) * Kstride + koff + skoff;
  #pragma unroll
  for (int j = 0; j < 2; j++)
    gB[j] = W + (size_t)(n0 + (w + 4 * j) * 16 + srow) * Kstride + koff + skoff;

  #define ISSUE(buf, k0)                                              \
    do {                                                              \
      _Pragma("unroll")                                               \
      for (int j = 0; j < NA; j++)                                    \
        gl_lds16(gA[j] + (k0), &sA[buf][(w + 4 * j) * 512]);          \
      _Pragma("unroll")                                               \
      for (int j = 0; j < 2; j++)                                     \
        gl_lds16(gB[j] + (k0), &sB[buf][(w + 4 * j) * 512]);          \
    } while (0)

  ISSUE(0, 0);
  ISSUE(1, 32);
  ISSUE(2, 64);
  int p = 0;
  for (int k0 = 0; k0 < K; k0 += 32) {
    // wait for tile t only: 2 younger tiles still in flight in steady state
    if (k0 + 64 < K) {
      asm volatile("s_waitcnt vmcnt(%0)\n\ts_barrier" :: "n"(2 * LPT) : "memory");
    } else if (k0 + 32 < K) {
      asm volatile("s_waitcnt vmcnt(%0)\n\ts_barrier" :: "n"(LPT) : "memory");
    } else {
      asm volatile("s_waitcnt vmcnt(0)\n\ts_barrier" ::: "memory");
    }
    if (k0 + 96 < K) {
      int nb = p + 3; if (nb >= 4) nb -= 4;
      ISSUE(nb, k0 + 96);
    }
    const bf16x8* fA = (const bf16x8*)sA[p];
    const bf16x8* fB = (const bf16x8*)sB[p];
    bf16x8 af[BM / 32], bfr[4];
    #pragma unroll
    for (int i = 0; i < BM / 32; i++) af[i]  = fA[(ga + i) * 64 + lane];
    #pragma unroll
    for (int j = 0; j < 4; j++)       bfr[j] = fB[(gb + j) * 64 + lane];
    #pragma unroll
    for (int i = 0; i < BM / 32; i++)
      #pragma unroll
      for (int j = 0; j < 4; j++)
        acc[i][j] = __builtin_amdgcn_mfma_f32_16x16x32_bf16(af[i], bfr[j], acc[i][j], 0, 0, 0);
    p++; if (p >= 4) p = 0;
  }
  #undef ISSUE

  const int q = lane >> 4, mm = lane & 15;
  #pragma unroll
  for (int i = 0; i < BM / 32; i++)
    #pragma unroll
    for (int j = 0; j < 4; j++) {
      int r0  = m0 + wm + i * 16 + q * 4;
      int col = n0 + wn + j * 16 + mm;
      #pragma unroll
      for (int r = 0; r < 4; r++) {
        float v = acc[i][j][r];
        if (EPI == 5) {
          if (col < DI) ((bf16*)Cv) [(size_t)(r0 + r) * DI + col]        = __float2bfloat16(v);
          else          ((bf16*)C2v)[(size_t)(r0 + r) * DI + (col - DI)] = __float2bfloat16(v);
        } else if (EPI == 6) {
          if (col < DI) {
            float vv = v + bias[col];
            vv = (vv > 15.f) ? vv : __logf(1.f + __expf(vv));
            ((bf16*)Cv)[(size_t)(r0 + r) * DI + col] = __float2bfloat16(vv);
          } else if (col < DI + 32) {
            ((float*)C2v)[(size_t)(r0 + r) * 32 + (col - DI)] = v;
          }
        } else {  // EPI == 7: split-K partial
          ((float*)Cv)[(size_t)blockIdx.z * M * N + (size_t)(r0 + r) * N + col] = v;
        }
      }
    }
}

// ---------------- split-K reduce: out = P0 + P1 (fp32, float4) ----------------
__global__ __launch_bounds__(256) void redk_k(const float4* __restrict__ P,
                                              float4* __restrict__ out, int n4) {
  int i = blockIdx.x * 256 + threadIdx.x;
  if (i >= n4) return;
  float4 a = P[i], b = P[i + n4];
  out[i] = make_float4(a.x + b.x, a.y + b.y, a.z + b.z, a.w + b.w);
}

// ---------------- depthwise causal conv (dc=4) + SiLU; bf16 in/out ----------------
__global__ __launch_bounds__(256) void conv_silu_k(const bf16* __restrict__ xpart,
                                                   const float* __restrict__ Wc,
                                                   __hip_bfloat16* __restrict__ xcbf) {
  int idx = blockIdx.x * 256 + threadIdx.x;
  if (idx >= MM * DI) return;
  int d = idx % DI;
  int r = idx / DI;
  int l = r & (LL - 1);
  float4 wv = ((const float4*)Wc)[d];  // W_conv[d, 0, 0..3]
  const bf16* xp = xpart + (size_t)r * DI + d;
  float acc = wv.w * __bfloat162float(xp[0]);
  if (l >= 1) acc += wv.z * __bfloat162float(xp[-(ptrdiff_t)DI]);
  if (l >= 2) acc += wv.y * __bfloat162float(xp[-(ptrdiff_t)(2 * DI)]);
  if (l >= 3) acc += wv.x * __bfloat162float(xp[-(ptrdiff_t)(3 * DI)]);
  float s = acc / (1.f + __expf(-acc));   // silu
  xcbf[idx] = __float2bfloat16(s);
}

// ================= chunked selective scan (NCH=64, CHL=32) =================
__global__ __launch_bounds__(64) void scan_part_k(const bf16* __restrict__ delta,
                                                  const float* __restrict__ xdbl,
                                                  const float* __restrict__ A_log,
                                                  float* __restrict__ prodA,
                                                  float* __restrict__ hend) {
  __shared__ float sBC[CHL * 32];
  const int t = threadIdx.x;
  const int dg = blockIdx.x % (DI / 64);
  const int chunk = (blockIdx.x / (DI / 64)) % NCH;
  const int b = blockIdx.x / ((DI / 64) * NCH);
  const int d = dg * 64 + t;

  float a[16];
  #pragma unroll
  for (int s = 0; s < 16; s++) a[s] = -__expf(A_log[s]);

  const float4* src = (const float4*)(xdbl + ((size_t)b * LL + chunk * CHL) * 32);
  #pragma unroll
  for (int k = 0; k < CHL * 32 / 4 / 64; k++) ((float4*)sBC)[t + k * 64] = src[t + k * 64];
  __syncthreads();

  float h[16], p[16];
  #pragma unroll
  for (int s = 0; s < 16; s++) { h[s] = 0.f; p[s] = 1.f; }

  const bf16* dptr = delta + ((size_t)b * LL + chunk * CHL) * DI + d;
  #pragma unroll 2
  for (int i = 0; i < CHL; i++) {
    float dlt = __bfloat162float(dptr[(size_t)i * DI]);
    const float4* bc = (const float4*)(sBC + i * 32);
    float4 B0 = bc[0], B1 = bc[1], B2 = bc[2], B3 = bc[3];
    float Bv[16] = {B0.x,B0.y,B0.z,B0.w, B1.x,B1.y,B1.z,B1.w,
                    B2.x,B2.y,B2.z,B2.w, B3.x,B3.y,B3.z,B3.w};
    #pragma unroll
    for (int s = 0; s < 16; s++) {
      float dA = __expf(dlt * a[s]);
      h[s] = dA * h[s] + dlt * Bv[s];
      p[s] *= dA;
    }
  }
  size_t o = (size_t)chunk * SEQS + ((size_t)b * DI + d) * 16;
  #pragma unroll
  for (int s = 0; s < 16; s += 4) {
    ((float4*)(prodA + o))[s >> 2] = make_float4(p[s], p[s+1], p[s+2], p[s+3]);
    ((float4*)(hend  + o))[s >> 2] = make_float4(h[s], h[s+1], h[s+2], h[s+3]);
  }
}

__global__ __launch_bounds__(64) void scan_comb_k(const float* __restrict__ prodA,
                                                  const float* __restrict__ hend,
                                                  float* __restrict__ hstart) {
  int idx = blockIdx.x * 64 + threadIdx.x;   // 0 .. SEQS-1
  float run = 0.f;
  #pragma unroll 4
  for (int c = 0; c < NCH; c++) {
    size_t o = (size_t)c * SEQS + idx;
    hstart[o] = run;
    run = prodA[o] * run + hend[o];
  }
}

__global__ __launch_bounds__(64) void scan_fin_k(const bf16* __restrict__ delta,
                                                 const float* __restrict__ xdbl,
                                                 const float* __restrict__ A_log,
                                                 const float* __restrict__ Dp,
                                                 const bf16* __restrict__ xcbf,
                                                 const bf16* __restrict__ zbf,
                                                 const float* __restrict__ hstart,
                                                 __hip_bfloat16* __restrict__ ypbf) {
  __shared__ float sBC[CHL * 32];
  const int t = threadIdx.x;
  const int dg = blockIdx.x % (DI / 64);
  const int chunk = (blockIdx.x / (DI / 64)) % NCH;
  const int b = blockIdx.x / ((DI / 64) * NCH);
  const int d = dg * 64 + t;

  float a[16];
  #pragma unroll
  for (int s = 0; s < 16; s++) a[s] = -__expf(A_log[s]);

  const float4* src = (const float4*)(xdbl + ((size_t)b * LL + chunk * CHL) * 32);
  #pragma unroll
  for (int k = 0; k < CHL * 32 / 4 / 64; k++) ((float4*)sBC)[t + k * 64] = src[t + k * 64];
  __syncthreads();

  float h[16];
  size_t o = (size_t)chunk * SEQS + ((size_t)b * DI + d) * 16;
  #pragma unroll
  for (int s = 0; s < 16; s += 4) {
    float4 v = ((const float4*)(hstart + o))[s >> 2];
    h[s] = v.x; h[s+1] = v.y; h[s+2] = v.z; h[s+3] = v.w;
  }
  const float Dv = Dp[d];

  const size_t rbase = (size_t)b * LL + chunk * CHL;
  const bf16* dptr = delta + rbase * DI + d;
  const bf16* xcp  = xcbf  + rbase * DI + d;
  const bf16* zp   = zbf   + rbase * DI + d;
  __hip_bfloat16* yp = ypbf + rbase * DI + d;

  #pragma unroll 2
  for (int i = 0; i < CHL; i++) {
    float dlt = __bfloat162float(dptr[(size_t)i * DI]);
    const float4* bc = (const float4*)(sBC + i * 32);
    float4 B0 = bc[0], B1 = bc[1], B2 = bc[2], B3 = bc[3];
    float4 C0 = bc[4], C1 = bc[5], C2 = bc[6], C3 = bc[7];
    float Bv[16] = {B0.x,B0.y,B0.z,B0.w, B1.x,B1.y,B1.z,B1.w,
                    B2.x,B2.y,B2.z,B2.w, B3.x,B3.y,B3.z,B3.w};
    float Cv[16] = {C0.x,C0.y,C0.z,C0.w, C1.x,C1.y,C1.z,C1.w,
                    C2.x,C2.y,C2.z,C2.w, C3.x,C3.y,C3.z,C3.w};
    float y = 0.f;
    #pragma unroll
    for (int s = 0; s < 16; s++) {
      float dA = __expf(dlt * a[s]);
      h[s] = dA * h[s] + dlt * Bv[s];
      y += h[s] * Cv[s];
    }
    float xcv = __bfloat162float(xcp[(size_t)i * DI]);
    float zv  = __bfloat162float(zp [(size_t)i * DI]);
    float val = (y + Dv * xcv) * (zv / (1.f + __expf(-zv)));
    yp[(size_t)i * DI] = __float2bfloat16(val);
  }
}

extern "C" void kernel_launch(void* const* d_in, const int* in_sizes, int n_in,
                              void* d_out, int out_size, void* d_ws, size_t ws_size,
                              hipStream_t stream) {
  const float* x      = (const float*)d_in[0];
  const float* W_in   = (const float*)d_in[1];
  const float* W_conv = (const float*)d_in[2];
  const float* W_x    = (const float*)d_in[3];
  const float* W_dt   = (const float*)d_in[4];
  const float* b_dt   = (const float*)d_in[5];
  const float* A_log  = (const float*)d_in[6];
  const float* Dp     = (const float*)d_in[7];
  const float* W_out  = (const float*)d_in[8];
  float* out = (float*)d_out;

  char* ws = (char*)d_ws;
  // workspace layout (bytes), max used = 119668736
  bf16*  xpartbf = (bf16*)(ws + 0);          // 12582912 (dead after conv)
  bf16*  zbf     = (bf16*)(ws + 12582912);   // 12582912 (dead after scan_fin)
  bf16*  xbf     = (bf16*)(ws + 25165824);   //  6291456 (dead after GEMM1)
  bf16*  Winbf   = (bf16*)(ws + 31457280);   //  4718592 (dead after GEMM1)
  bf16*  xcbf    = (bf16*)(ws + 36175872);   // 12582912
  bf16*  Wcomb   = (bf16*)(ws + 48758784);   //  5111808
  bf16*  deltabf = (bf16*)(ws + 53870592);   // 12582912
  float* xdbl    = (float*)(ws + 66453504);  //   524288
  bf16*  ypbf    = (bf16*)(ws + 66977792);   // 12582912
  bf16*  Woutbf  = (bf16*)(ws + 79560704);   //  2359296
  float* prodA   = (float*)(ws + 81920000);  // 64*49152*4 = 12582912
  float* hend    = (float*)(ws + 94502912);  // 12582912
  float* hstart  = (float*)(ws + 107085824); // 12582912
  // GEMM3 split-K partials alias [0, 25165824) (xpartbf+zbf, both dead by then):
  float* P3      = (float*)(ws + 0);         // 2 * 4096*768*4 = 25165824

  // merged prep: bf16 converts + Wcomb build
  prep_k<<<(PRTOT + 255) / 256, 256, 0, stream>>>(x, W_in, W_out, W_dt, W_x,
                                                  xbf, Winbf, Woutbf, Wcomb);

  // xz = x @ W_in.T (4096 x 3072, K=768), split bf16 stores into xpartbf | zbf
  {
    dim3 g(3072 / 128, 4096 / 128, 1);   // 768 blocks
    gemm_db<5, 128><<<g, 256, 0, stream>>>(xbf, Winbf, xpartbf, zbf, nullptr,
                                           MM, 2 * DI, DM, DM);
  }
  // xc = silu(causal_dwconv(xpart)), bf16
  conv_silu_k<<<(MM * DI + 255) / 256, 256, 0, stream>>>(xpartbf, W_conv, xcbf);
  // delta = bf16(softplus(xc @ W_dt.T + b_dt)) AND xdbl = xc @ W_x.T (fp32)
  {
    dim3 g(NC2 / 128, 4096 / 128, 1);    // 416 blocks
    gemm_db<6, 128><<<g, 256, 0, stream>>>(xcbf, Wcomb, deltabf, xdbl, b_dt,
                                           MM, NC2, DI, DI);
  }
  // chunked selective scan + gating (NCH=64 -> 3072 blocks, 12 waves/CU)
  scan_part_k<<<BB * NCH * (DI / 64), 64, 0, stream>>>(deltabf, xdbl, A_log, prodA, hend);
  scan_comb_k<<<SEQS / 64, 64, 0, stream>>>(prodA, hend, hstart);
  scan_fin_k<<<BB * NCH * (DI / 64), 64, 0, stream>>>(deltabf, xdbl, A_log, Dp, xcbf, zbf,
                                                      hstart, ypbf);
  // out = y @ W_out.T (4096 x 768, K=1536): split-K=2, partials + reduce
  {
    dim3 g(768 / 128, 4096 / 128, 2);
    gemm_db<7, 128><<<g, 256, 0, stream>>>(ypbf, Woutbf, P3, nullptr, nullptr,
                                           MM, DM, DI / 2, DI);
  }
  redk_k<<<(786432 + 255) / 256, 256, 0, stream>>>((const float4*)P3, (float4*)out, 786432);
}

// Round 5
// 332.473 us; speedup vs baseline: 1.1811x; 1.0450x over previous
//
#include <hip/hip_runtime.h>
#include <hip/hip_bf16.h>

// Problem constants (B=2, L=2048, Dm=768, di=1536, ds=16, dc=4)
#define BB 2
#define LL 2048
#define DM 768
#define DI 1536
#define DS 16
#define MM (BB*LL)   // 4096 rows
#define NCH 64       // scan chunks
#define CHL 32       // steps per chunk
#define SEQS (BB*DI*DS)  // 49152 independent scalar recurrences
#define NC2 1664     // delta GEMM fused N: 1536 (W_dt) + 32 (W_x) + 96 pad

typedef __hip_bfloat16 bf16;
typedef short bf16x8 __attribute__((ext_vector_type(8)));
typedef float f32x4  __attribute__((ext_vector_type(4)));

__device__ __forceinline__ void gl_lds16(const void* g, void* l) {
  __builtin_amdgcn_global_load_lds((const __attribute__((address_space(1))) void*)g,
                                   (__attribute__((address_space(3))) void*)l, 16, 0, 0);
}

// Inline-asm ds_read_b128: OPAQUE to the compiler's waitcnt-insertion pass.
// Rationale (r4 post-mortem): compiler-visible LDS reads of global_load_lds-
// written buffers force a conservative s_waitcnt vmcnt(0) drain every K-iter
// (runtime-rotating buffer index is unanalyzable), defeating the counted
// pipeline. Opaque reads + manual lgkmcnt keep the counted vmcnt in charge.
__device__ __forceinline__ bf16x8 ds_frag(const short* lds) {
  bf16x8 r;
  unsigned off = (unsigned)(uintptr_t)(const __attribute__((address_space(3))) short*)lds;
  asm volatile("ds_read_b128 %0, %1" : "=v"(r) : "v"(off));
  return r;
}

// ---------------- merged prep: x/W_in/W_out -> bf16, build Wcomb ----------------
struct bf4 { __hip_bfloat16 a, b, c, d; };
#define PR0 786432                   // x: 4096*768/4
#define PR1 589824                   // W_in: 3072*768/4
#define PR2 294912                   // W_out: 768*1536/4
#define PR3 638976                   // Wcomb: 1664*1536/4
#define PRTOT (PR0+PR1+PR2+PR3)      // 2310144

__global__ __launch_bounds__(256) void prep_k(const float* __restrict__ x,
                                              const float* __restrict__ Win,
                                              const float* __restrict__ Wout,
                                              const float* __restrict__ Wdt,
                                              const float* __restrict__ Wx,
                                              __hip_bfloat16* __restrict__ xbf,
                                              __hip_bfloat16* __restrict__ Winbf,
                                              __hip_bfloat16* __restrict__ Woutbf,
                                              __hip_bfloat16* __restrict__ Wcomb) {
  int i = blockIdx.x * 256 + threadIdx.x;
  if (i >= PRTOT) return;
  float4 v; __hip_bfloat16* dst; int di_;
  if (i < PR0)                    { v = ((const float4*)x)[i];                 dst = xbf;    di_ = i; }
  else if (i < PR0 + PR1)         { di_ = i - PR0; v = ((const float4*)Win)[di_];  dst = Winbf; }
  else if (i < PR0 + PR1 + PR2)   { di_ = i - PR0 - PR1; v = ((const float4*)Wout)[di_]; dst = Woutbf; }
  else {
    di_ = i - PR0 - PR1 - PR2;    // Wcomb = [W_dt ; W_x ; 0-pad]
    int e = di_ * 4, row = e / DI, colb = e % DI;
    if (row < DI)            v = ((const float4*)Wdt)[di_];
    else if (row < DI + 32)  v = *(const float4*)(Wx + (size_t)(row - DI) * DI + colb);
    else                     v = make_float4(0.f, 0.f, 0.f, 0.f);
    dst = Wcomb;
  }
  bf4 o = { __float2bfloat16(v.x), __float2bfloat16(v.y),
            __float2bfloat16(v.z), __float2bfloat16(v.w) };
  ((bf4*)dst)[di_] = o;
}

// ---------------- pipelined LDS-staged GEMM, depth-3, opaque frag reads --------
// C[M,N] = A[M,K_sub] * W[N,K_sub]^T. BM=128/256, BN=128. 256 threads = 4 waves
// (2x2), wave tile (BM/2)x64. 4 LDS buffers, 3 tiles in flight, counted
// vmcnt + raw s_barrier per iter; fragment loads via inline-asm ds_read_b128
// + lgkmcnt(0) + sched_barrier(0) (rule #18).
// EPI: 5 = split bf16: col<DI -> C (stride DI), else -> C2 (stride DI) [xz GEMM]
//      6 = col<DI -> bf16(softplus(v+bias[col])) -> C (stride DI);
//          col in [DI,DI+32) -> fp32 C2 (stride 32); else discard   [delta+xdbl]
//      7 = fp32 partial store at C + blockIdx.z*M*N                 [split-K]
template<int EPI, int BM>
__global__ __launch_bounds__(256) void gemm_db(const bf16* __restrict__ A,
                                               const bf16* __restrict__ W,
                                               void* __restrict__ Cv,
                                               void* __restrict__ C2v,
                                               const float* __restrict__ bias,
                                               int M, int N, int K, int Kstride) {
  constexpr int NA  = BM / 64;
  constexpr int LPT = NA + 2;     // gl_lds16 per thread per tile
  __shared__ short sA[4][BM * 32];
  __shared__ short sB[4][128 * 32];
  const int t = threadIdx.x;
  const int m0 = blockIdx.y * BM, n0 = blockIdx.x * 128;
  const size_t koff = (size_t)blockIdx.z * K;
  const int w = t >> 6, lane = t & 63;
  const int wm = (w >> 1) * (BM / 2), wn = (w & 1) * 64;
  const int ga = wm >> 4, gb = wn >> 4;

  f32x4 acc[BM / 32][4] = {};

  const int srow = lane & 15, skoff = (lane >> 4) * 8;
  const bf16* gA[NA]; const bf16* gB[2];
  #pragma unroll
  for (int j = 0; j < NA; j++)
    gA[j] = A + (size_t)(m0 + (w + 4 * j) * 16 + srow) * Kstride + koff + skoff;
  #pragma unroll
  for (int j = 0; j < 2; j++)
    gB[j] = W + (size_t)(n0 + (w + 4 * j) * 16 + srow) * Kstride + koff + skoff;

  #define ISSUE(buf, k0)                                              \
    do {                                                              \
      _Pragma("unroll")                                               \
      for (int j = 0; j < NA; j++)                                    \
        gl_lds16(gA[j] + (k0), &sA[buf][(w + 4 * j) * 512]);          \
      _Pragma("unroll")                                               \
      for (int j = 0; j < 2; j++)                                     \
        gl_lds16(gB[j] + (k0), &sB[buf][(w + 4 * j) * 512]);          \
    } while (0)

  ISSUE(0, 0);
  ISSUE(1, 32);
  ISSUE(2, 64);
  int p = 0;
  for (int k0 = 0; k0 < K; k0 += 32) {
    // wait for tile t only: up to 2 younger tiles stay in flight
    if (k0 + 64 < K) {
      asm volatile("s_waitcnt vmcnt(%0)" :: "n"(2 * LPT));
    } else if (k0 + 32 < K) {
      asm volatile("s_waitcnt vmcnt(%0)" :: "n"(LPT));
    } else {
      asm volatile("s_waitcnt vmcnt(0)");
    }
    __builtin_amdgcn_s_barrier();
    if (k0 + 96 < K) {
      int nb = p + 3; if (nb >= 4) nb -= 4;
      ISSUE(nb, k0 + 96);
    }
    const short* baseA = sA[p];
    const short* baseB = sB[p];
    bf16x8 af[BM / 32], bfr[4];
    #pragma unroll
    for (int i = 0; i < BM / 32; i++) af[i]  = ds_frag(baseA + ((ga + i) * 64 + lane) * 8);
    #pragma unroll
    for (int j = 0; j < 4; j++)       bfr[j] = ds_frag(baseB + ((gb + j) * 64 + lane) * 8);
    asm volatile("s_waitcnt lgkmcnt(0)");
    __builtin_amdgcn_sched_barrier(0);
    #pragma unroll
    for (int i = 0; i < BM / 32; i++)
      #pragma unroll
      for (int j = 0; j < 4; j++)
        acc[i][j] = __builtin_amdgcn_mfma_f32_16x16x32_bf16(af[i], bfr[j], acc[i][j], 0, 0, 0);
    p++; if (p >= 4) p = 0;
  }
  #undef ISSUE

  const int q = lane >> 4, mm = lane & 15;
  #pragma unroll
  for (int i = 0; i < BM / 32; i++)
    #pragma unroll
    for (int j = 0; j < 4; j++) {
      int r0  = m0 + wm + i * 16 + q * 4;
      int col = n0 + wn + j * 16 + mm;
      #pragma unroll
      for (int r = 0; r < 4; r++) {
        float v = acc[i][j][r];
        if (EPI == 5) {
          if (col < DI) ((bf16*)Cv) [(size_t)(r0 + r) * DI + col]        = __float2bfloat16(v);
          else          ((bf16*)C2v)[(size_t)(r0 + r) * DI + (col - DI)] = __float2bfloat16(v);
        } else if (EPI == 6) {
          if (col < DI) {
            float vv = v + bias[col];
            vv = (vv > 15.f) ? vv : __logf(1.f + __expf(vv));
            ((bf16*)Cv)[(size_t)(r0 + r) * DI + col] = __float2bfloat16(vv);
          } else if (col < DI + 32) {
            ((float*)C2v)[(size_t)(r0 + r) * 32 + (col - DI)] = v;
          }
        } else {  // EPI == 7: split-K partial
          ((float*)Cv)[(size_t)blockIdx.z * M * N + (size_t)(r0 + r) * N + col] = v;
        }
      }
    }
}

// ---------------- split-K reduce: out = P0 + P1 (fp32, float4) ----------------
__global__ __launch_bounds__(256) void redk_k(const float4* __restrict__ P,
                                              float4* __restrict__ out, int n4) {
  int i = blockIdx.x * 256 + threadIdx.x;
  if (i >= n4) return;
  float4 a = P[i], b = P[i + n4];
  out[i] = make_float4(a.x + b.x, a.y + b.y, a.z + b.z, a.w + b.w);
}

// ---------------- depthwise causal conv (dc=4) + SiLU; bf16 in/out ----------------
__global__ __launch_bounds__(256) void conv_silu_k(const bf16* __restrict__ xpart,
                                                   const float* __restrict__ Wc,
                                                   __hip_bfloat16* __restrict__ xcbf) {
  int idx = blockIdx.x * 256 + threadIdx.x;
  if (idx >= MM * DI) return;
  int d = idx % DI;
  int r = idx / DI;
  int l = r & (LL - 1);
  float4 wv = ((const float4*)Wc)[d];  // W_conv[d, 0, 0..3]
  const bf16* xp = xpart + (size_t)r * DI + d;
  float acc = wv.w * __bfloat162float(xp[0]);
  if (l >= 1) acc += wv.z * __bfloat162float(xp[-(ptrdiff_t)DI]);
  if (l >= 2) acc += wv.y * __bfloat162float(xp[-(ptrdiff_t)(2 * DI)]);
  if (l >= 3) acc += wv.x * __bfloat162float(xp[-(ptrdiff_t)(3 * DI)]);
  float s = acc / (1.f + __expf(-acc));   // silu
  xcbf[idx] = __float2bfloat16(s);
}

// ================= chunked selective scan (NCH=64, CHL=32) =================
__global__ __launch_bounds__(64) void scan_part_k(const bf16* __restrict__ delta,
                                                  const float* __restrict__ xdbl,
                                                  const float* __restrict__ A_log,
                                                  float* __restrict__ prodA,
                                                  float* __restrict__ hend) {
  __shared__ float sBC[CHL * 32];
  const int t = threadIdx.x;
  const int dg = blockIdx.x % (DI / 64);
  const int chunk = (blockIdx.x / (DI / 64)) % NCH;
  const int b = blockIdx.x / ((DI / 64) * NCH);
  const int d = dg * 64 + t;

  float a[16];
  #pragma unroll
  for (int s = 0; s < 16; s++) a[s] = -__expf(A_log[s]);

  const float4* src = (const float4*)(xdbl + ((size_t)b * LL + chunk * CHL) * 32);
  #pragma unroll
  for (int k = 0; k < CHL * 32 / 4 / 64; k++) ((float4*)sBC)[t + k * 64] = src[t + k * 64];
  __syncthreads();

  float h[16], p[16];
  #pragma unroll
  for (int s = 0; s < 16; s++) { h[s] = 0.f; p[s] = 1.f; }

  const bf16* dptr = delta + ((size_t)b * LL + chunk * CHL) * DI + d;
  #pragma unroll 2
  for (int i = 0; i < CHL; i++) {
    float dlt = __bfloat162float(dptr[(size_t)i * DI]);
    const float4* bc = (const float4*)(sBC + i * 32);
    float4 B0 = bc[0], B1 = bc[1], B2 = bc[2], B3 = bc[3];
    float Bv[16] = {B0.x,B0.y,B0.z,B0.w, B1.x,B1.y,B1.z,B1.w,
                    B2.x,B2.y,B2.z,B2.w, B3.x,B3.y,B3.z,B3.w};
    #pragma unroll
    for (int s = 0; s < 16; s++) {
      float dA = __expf(dlt * a[s]);
      h[s] = dA * h[s] + dlt * Bv[s];
      p[s] *= dA;
    }
  }
  size_t o = (size_t)chunk * SEQS + ((size_t)b * DI + d) * 16;
  #pragma unroll
  for (int s = 0; s < 16; s += 4) {
    ((float4*)(prodA + o))[s >> 2] = make_float4(p[s], p[s+1], p[s+2], p[s+3]);
    ((float4*)(hend  + o))[s >> 2] = make_float4(h[s], h[s+1], h[s+2], h[s+3]);
  }
}

__global__ __launch_bounds__(64) void scan_comb_k(const float* __restrict__ prodA,
                                                  const float* __restrict__ hend,
                                                  float* __restrict__ hstart) {
  int idx = blockIdx.x * 64 + threadIdx.x;   // 0 .. SEQS-1
  float run = 0.f;
  #pragma unroll 4
  for (int c = 0; c < NCH; c++) {
    size_t o = (size_t)c * SEQS + idx;
    hstart[o] = run;
    run = prodA[o] * run + hend[o];
  }
}

__global__ __launch_bounds__(64) void scan_fin_k(const bf16* __restrict__ delta,
                                                 const float* __restrict__ xdbl,
                                                 const float* __restrict__ A_log,
                                                 const float* __restrict__ Dp,
                                                 const bf16* __restrict__ xcbf,
                                                 const bf16* __restrict__ zbf,
                                                 const float* __restrict__ hstart,
                                                 __hip_bfloat16* __restrict__ ypbf) {
  __shared__ float sBC[CHL * 32];
  const int t = threadIdx.x;
  const int dg = blockIdx.x % (DI / 64);
  const int chunk = (blockIdx.x / (DI / 64)) % NCH;
  const int b = blockIdx.x / ((DI / 64) * NCH);
  const int d = dg * 64 + t;

  float a[16];
  #pragma unroll
  for (int s = 0; s < 16; s++) a[s] = -__expf(A_log[s]);

  const float4* src = (const float4*)(xdbl + ((size_t)b * LL + chunk * CHL) * 32);
  #pragma unroll
  for (int k = 0; k < CHL * 32 / 4 / 64; k++) ((float4*)sBC)[t + k * 64] = src[t + k * 64];
  __syncthreads();

  float h[16];
  size_t o = (size_t)chunk * SEQS + ((size_t)b * DI + d) * 16;
  #pragma unroll
  for (int s = 0; s < 16; s += 4) {
    float4 v = ((const float4*)(hstart + o))[s >> 2];
    h[s] = v.x; h[s+1] = v.y; h[s+2] = v.z; h[s+3] = v.w;
  }
  const float Dv = Dp[d];

  const size_t rbase = (size_t)b * LL + chunk * CHL;
  const bf16* dptr = delta + rbase * DI + d;
  const bf16* xcp  = xcbf  + rbase * DI + d;
  const bf16* zp   = zbf   + rbase * DI + d;
  __hip_bfloat16* yp = ypbf + rbase * DI + d;

  #pragma unroll 2
  for (int i = 0; i < CHL; i++) {
    float dlt = __bfloat162float(dptr[(size_t)i * DI]);
    const float4* bc = (const float4*)(sBC + i * 32);
    float4 B0 = bc[0], B1 = bc[1], B2 = bc[2], B3 = bc[3];
    float4 C0 = bc[4], C1 = bc[5], C2 = bc[6], C3 = bc[7];
    float Bv[16] = {B0.x,B0.y,B0.z,B0.w, B1.x,B1.y,B1.z,B1.w,
                    B2.x,B2.y,B2.z,B2.w, B3.x,B3.y,B3.z,B3.w};
    float Cv[16] = {C0.x,C0.y,C0.z,C0.w, C1.x,C1.y,C1.z,C1.w,
                    C2.x,C2.y,C2.z,C2.w, C3.x,C3.y,C3.z,C3.w};
    float y = 0.f;
    #pragma unroll
    for (int s = 0; s < 16; s++) {
      float dA = __expf(dlt * a[s]);
      h[s] = dA * h[s] + dlt * Bv[s];
      y += h[s] * Cv[s];
    }
    float xcv = __bfloat162float(xcp[(size_t)i * DI]);
    float zv  = __bfloat162float(zp [(size_t)i * DI]);
    float val = (y + Dv * xcv) * (zv / (1.f + __expf(-zv)));
    yp[(size_t)i * DI] = __float2bfloat16(val);
  }
}

extern "C" void kernel_launch(void* const* d_in, const int* in_sizes, int n_in,
                              void* d_out, int out_size, void* d_ws, size_t ws_size,
                              hipStream_t stream) {
  const float* x      = (const float*)d_in[0];
  const float* W_in   = (const float*)d_in[1];
  const float* W_conv = (const float*)d_in[2];
  const float* W_x    = (const float*)d_in[3];
  const float* W_dt   = (const float*)d_in[4];
  const float* b_dt   = (const float*)d_in[5];
  const float* A_log  = (const float*)d_in[6];
  const float* Dp     = (const float*)d_in[7];
  const float* W_out  = (const float*)d_in[8];
  float* out = (float*)d_out;

  char* ws = (char*)d_ws;
  // workspace layout (bytes), max used = 119668736
  bf16*  xpartbf = (bf16*)(ws + 0);          // 12582912 (dead after conv)
  bf16*  zbf     = (bf16*)(ws + 12582912);   // 12582912 (dead after scan_fin)
  bf16*  xbf     = (bf16*)(ws + 25165824);   //  6291456 (dead after GEMM1)
  bf16*  Winbf   = (bf16*)(ws + 31457280);   //  4718592 (dead after GEMM1)
  bf16*  xcbf    = (bf16*)(ws + 36175872);   // 12582912
  bf16*  Wcomb   = (bf16*)(ws + 48758784);   //  5111808
  bf16*  deltabf = (bf16*)(ws + 53870592);   // 12582912
  float* xdbl    = (float*)(ws + 66453504);  //   524288
  bf16*  ypbf    = (bf16*)(ws + 66977792);   // 12582912
  bf16*  Woutbf  = (bf16*)(ws + 79560704);   //  2359296
  float* prodA   = (float*)(ws + 81920000);  // 64*49152*4 = 12582912
  float* hend    = (float*)(ws + 94502912);  // 12582912
  float* hstart  = (float*)(ws + 107085824); // 12582912
  // GEMM3 split-K partials alias [0, 25165824) (xpartbf+zbf, both dead by then):
  float* P3      = (float*)(ws + 0);         // 2 * 4096*768*4 = 25165824

  // merged prep: bf16 converts + Wcomb build
  prep_k<<<(PRTOT + 255) / 256, 256, 0, stream>>>(x, W_in, W_out, W_dt, W_x,
                                                  xbf, Winbf, Woutbf, Wcomb);

  // xz = x @ W_in.T (4096 x 3072, K=768), split bf16 stores into xpartbf | zbf
  {
    dim3 g(3072 / 128, 4096 / 128, 1);   // 768 blocks
    gemm_db<5, 128><<<g, 256, 0, stream>>>(xbf, Winbf, xpartbf, zbf, nullptr,
                                           MM, 2 * DI, DM, DM);
  }
  // xc = silu(causal_dwconv(xpart)), bf16
  conv_silu_k<<<(MM * DI + 255) / 256, 256, 0, stream>>>(xpartbf, W_conv, xcbf);
  // delta = bf16(softplus(xc @ W_dt.T + b_dt)) AND xdbl = xc @ W_x.T (fp32)
  {
    dim3 g(NC2 / 128, 4096 / 128, 1);    // 416 blocks
    gemm_db<6, 128><<<g, 256, 0, stream>>>(xcbf, Wcomb, deltabf, xdbl, b_dt,
                                           MM, NC2, DI, DI);
  }
  // chunked selective scan + gating (NCH=64 -> 3072 blocks, 12 waves/CU)
  scan_part_k<<<BB * NCH * (DI / 64), 64, 0, stream>>>(deltabf, xdbl, A_log, prodA, hend);
  scan_comb_k<<<SEQS / 64, 64, 0, stream>>>(prodA, hend, hstart);
  scan_fin_k<<<BB * NCH * (DI / 64), 64, 0, stream>>>(deltabf, xdbl, A_log, Dp, xcbf, zbf,
                                                      hstart, ypbf);
  // out = y @ W_out.T (4096 x 768, K=1536): split-K=2, partials + reduce
  {
    dim3 g(768 / 128, 4096 / 128, 2);
    gemm_db<7, 128><<<g, 256, 0, stream>>>(ypbf, Woutbf, P3, nullptr, nullptr,
                                           MM, DM, DI / 2, DI);
  }
  redk_k<<<(786432 + 255) / 256, 256, 0, stream>>>((const float4*)P3, (float4*)out, 786432);
}

// Round 6
// 329.767 us; speedup vs baseline: 1.1908x; 1.0082x over previous
//
#include <hip/hip_runtime.h>
#include <hip/hip_bf16.h>

// Problem constants (B=2, L=2048, Dm=768, di=1536, ds=16, dc=4)
#define BB 2
#define LL 2048
#define DM 768
#define DI 1536
#define DS 16
#define MM (BB*LL)   // 4096 rows
#define NCH 64       // scan chunks
#define CHL 32       // steps per chunk
#define SEQS (BB*DI*DS)  // 49152 independent scalar recurrences
#define NC2 1664     // delta GEMM fused N: 1536 (W_dt) + 32 (W_x) + 96 pad

typedef __hip_bfloat16 bf16;
typedef short bf16x8 __attribute__((ext_vector_type(8)));
typedef float f32x4  __attribute__((ext_vector_type(4)));

__device__ __forceinline__ void gl_lds16(const void* g, void* l) {
  __builtin_amdgcn_global_load_lds((const __attribute__((address_space(1))) void*)g,
                                   (__attribute__((address_space(3))) void*)l, 16, 0, 0);
}

// Inline-asm ds_read_b128: OPAQUE to the compiler's waitcnt-insertion pass
// (r4/r5: visible LDS reads of global_load_lds targets force vmcnt(0) drains).
__device__ __forceinline__ bf16x8 ds_frag(const short* lds) {
  bf16x8 r;
  unsigned off = (unsigned)(uintptr_t)(const __attribute__((address_space(3))) short*)lds;
  asm volatile("ds_read_b128 %0, %1" : "=v"(r) : "v"(off));
  return r;
}

// ---------------- merged prep: x/W_in/W_out -> bf16, build Wcomb ----------------
struct bf4 { __hip_bfloat16 a, b, c, d; };
#define PR0 786432                   // x: 4096*768/4
#define PR1 589824                   // W_in: 3072*768/4
#define PR2 294912                   // W_out: 768*1536/4
#define PR3 638976                   // Wcomb: 1664*1536/4
#define PRTOT (PR0+PR1+PR2+PR3)      // 2310144

__global__ __launch_bounds__(256) void prep_k(const float* __restrict__ x,
                                              const float* __restrict__ Win,
                                              const float* __restrict__ Wout,
                                              const float* __restrict__ Wdt,
                                              const float* __restrict__ Wx,
                                              __hip_bfloat16* __restrict__ xbf,
                                              __hip_bfloat16* __restrict__ Winbf,
                                              __hip_bfloat16* __restrict__ Woutbf,
                                              __hip_bfloat16* __restrict__ Wcomb) {
  int i = blockIdx.x * 256 + threadIdx.x;
  if (i >= PRTOT) return;
  float4 v; __hip_bfloat16* dst; int di_;
  if (i < PR0)                    { v = ((const float4*)x)[i];                 dst = xbf;    di_ = i; }
  else if (i < PR0 + PR1)         { di_ = i - PR0; v = ((const float4*)Win)[di_];  dst = Winbf; }
  else if (i < PR0 + PR1 + PR2)   { di_ = i - PR0 - PR1; v = ((const float4*)Wout)[di_]; dst = Woutbf; }
  else {
    di_ = i - PR0 - PR1 - PR2;    // Wcomb = [W_dt ; W_x ; 0-pad]
    int e = di_ * 4, row = e / DI, colb = e % DI;
    if (row < DI)            v = ((const float4*)Wdt)[di_];
    else if (row < DI + 32)  v = *(const float4*)(Wx + (size_t)(row - DI) * DI + colb);
    else                     v = make_float4(0.f, 0.f, 0.f, 0.f);
    dst = Wcomb;
  }
  bf4 o = { __float2bfloat16(v.x), __float2bfloat16(v.y),
            __float2bfloat16(v.z), __float2bfloat16(v.w) };
  ((bf4*)dst)[di_] = o;
}

// ---------------- pipelined LDS-staged GEMM, depth-3, opaque frag reads --------
// + T1 XCD-aware block swizzle (r5: FETCH = 5.4x unique bytes — each of the 8
//   XCD-private L2s refetched the full A panel. Bijective remap gives each XCD
//   a contiguous y-stripe (and one z for split-K). Requires grid % 8 == 0 —
//   holds for all three launches (416, 768, 768).)
// EPI: 5 = split bf16: col<DI -> C (stride DI), else -> C2 (stride DI) [xz GEMM]
//      6 = col<DI -> bf16(softplus(v+bias[col])) -> C (stride DI);
//          col in [DI,DI+32) -> fp32 C2 (stride 32); else discard   [delta+xdbl]
//      7 = fp32 partial store at C + wz*M*N                         [split-K]
template<int EPI, int BM>
__global__ __launch_bounds__(256) void gemm_db(const bf16* __restrict__ A,
                                               const bf16* __restrict__ W,
                                               void* __restrict__ Cv,
                                               void* __restrict__ C2v,
                                               const float* __restrict__ bias,
                                               int M, int N, int K, int Kstride) {
  constexpr int NA  = BM / 64;
  constexpr int LPT = NA + 2;     // gl_lds16 per thread per tile
  __shared__ short sA[4][BM * 32];
  __shared__ short sB[4][128 * 32];
  const int t = threadIdx.x;

  // T1 swizzle: hw dispatch id -> per-XCD contiguous work range
  const int gx = gridDim.x, gy = gridDim.y;
  const int n3 = gx * gy * gridDim.z;
  const int hw = blockIdx.x + gx * (blockIdx.y + gy * blockIdx.z);
  const int per = n3 >> 3;                  // n3 % 8 == 0 by launch config
  const int wl  = (hw & 7) * per + (hw >> 3);
  const int wz  = wl / (gx * gy);
  const int rem = wl - wz * (gx * gy);
  const int wy  = rem / gx, wx = rem - wy * gx;

  const int m0 = wy * BM, n0 = wx * 128;
  const size_t koff = (size_t)wz * K;
  const int w = t >> 6, lane = t & 63;
  const int wm = (w >> 1) * (BM / 2), wn = (w & 1) * 64;
  const int ga = wm >> 4, gb = wn >> 4;

  f32x4 acc[BM / 32][4] = {};

  const int srow = lane & 15, skoff = (lane >> 4) * 8;
  const bf16* gA[NA]; const bf16* gB[2];
  #pragma unroll
  for (int j = 0; j < NA; j++)
    gA[j] = A + (size_t)(m0 + (w + 4 * j) * 16 + srow) * Kstride + koff + skoff;
  #pragma unroll
  for (int j = 0; j < 2; j++)
    gB[j] = W + (size_t)(n0 + (w + 4 * j) * 16 + srow) * Kstride + koff + skoff;

  #define ISSUE(buf, k0)                                              \
    do {                                                              \
      _Pragma("unroll")                                               \
      for (int j = 0; j < NA; j++)                                    \
        gl_lds16(gA[j] + (k0), &sA[buf][(w + 4 * j) * 512]);          \
      _Pragma("unroll")                                               \
      for (int j = 0; j < 2; j++)                                     \
        gl_lds16(gB[j] + (k0), &sB[buf][(w + 4 * j) * 512]);          \
    } while (0)

  ISSUE(0, 0);
  ISSUE(1, 32);
  ISSUE(2, 64);
  int p = 0;
  for (int k0 = 0; k0 < K; k0 += 32) {
    // wait for tile t only: up to 2 younger tiles stay in flight
    if (k0 + 64 < K) {
      asm volatile("s_waitcnt vmcnt(%0)" :: "n"(2 * LPT));
    } else if (k0 + 32 < K) {
      asm volatile("s_waitcnt vmcnt(%0)" :: "n"(LPT));
    } else {
      asm volatile("s_waitcnt vmcnt(0)");
    }
    __builtin_amdgcn_s_barrier();
    if (k0 + 96 < K) {
      int nb = p + 3; if (nb >= 4) nb -= 4;
      ISSUE(nb, k0 + 96);
    }
    const short* baseA = sA[p];
    const short* baseB = sB[p];
    bf16x8 af[BM / 32], bfr[4];
    #pragma unroll
    for (int i = 0; i < BM / 32; i++) af[i]  = ds_frag(baseA + ((ga + i) * 64 + lane) * 8);
    #pragma unroll
    for (int j = 0; j < 4; j++)       bfr[j] = ds_frag(baseB + ((gb + j) * 64 + lane) * 8);
    asm volatile("s_waitcnt lgkmcnt(0)");
    __builtin_amdgcn_sched_barrier(0);
    #pragma unroll
    for (int i = 0; i < BM / 32; i++)
      #pragma unroll
      for (int j = 0; j < 4; j++)
        acc[i][j] = __builtin_amdgcn_mfma_f32_16x16x32_bf16(af[i], bfr[j], acc[i][j], 0, 0, 0);
    p++; if (p >= 4) p = 0;
  }
  #undef ISSUE

  const int q = lane >> 4, mm = lane & 15;
  #pragma unroll
  for (int i = 0; i < BM / 32; i++)
    #pragma unroll
    for (int j = 0; j < 4; j++) {
      int r0  = m0 + wm + i * 16 + q * 4;
      int col = n0 + wn + j * 16 + mm;
      #pragma unroll
      for (int r = 0; r < 4; r++) {
        float v = acc[i][j][r];
        if (EPI == 5) {
          if (col < DI) ((bf16*)Cv) [(size_t)(r0 + r) * DI + col]        = __float2bfloat16(v);
          else          ((bf16*)C2v)[(size_t)(r0 + r) * DI + (col - DI)] = __float2bfloat16(v);
        } else if (EPI == 6) {
          if (col < DI) {
            float vv = v + bias[col];
            vv = (vv > 15.f) ? vv : __logf(1.f + __expf(vv));
            ((bf16*)Cv)[(size_t)(r0 + r) * DI + col] = __float2bfloat16(vv);
          } else if (col < DI + 32) {
            ((float*)C2v)[(size_t)(r0 + r) * 32 + (col - DI)] = v;
          }
        } else {  // EPI == 7: split-K partial
          ((float*)Cv)[(size_t)wz * M * N + (size_t)(r0 + r) * N + col] = v;
        }
      }
    }
}

// ---------------- split-K reduce: out = P0 + P1 (fp32, float4) ----------------
__global__ __launch_bounds__(256) void redk_k(const float4* __restrict__ P,
                                              float4* __restrict__ out, int n4) {
  int i = blockIdx.x * 256 + threadIdx.x;
  if (i >= n4) return;
  float4 a = P[i], b = P[i + n4];
  out[i] = make_float4(a.x + b.x, a.y + b.y, a.z + b.z, a.w + b.w);
}

// ---------------- depthwise causal conv (dc=4) + SiLU; bf16 in/out ----------------
__global__ __launch_bounds__(256) void conv_silu_k(const bf16* __restrict__ xpart,
                                                   const float* __restrict__ Wc,
                                                   __hip_bfloat16* __restrict__ xcbf) {
  int idx = blockIdx.x * 256 + threadIdx.x;
  if (idx >= MM * DI) return;
  int d = idx % DI;
  int r = idx / DI;
  int l = r & (LL - 1);
  float4 wv = ((const float4*)Wc)[d];  // W_conv[d, 0, 0..3]
  const bf16* xp = xpart + (size_t)r * DI + d;
  float acc = wv.w * __bfloat162float(xp[0]);
  if (l >= 1) acc += wv.z * __bfloat162float(xp[-(ptrdiff_t)DI]);
  if (l >= 2) acc += wv.y * __bfloat162float(xp[-(ptrdiff_t)(2 * DI)]);
  if (l >= 3) acc += wv.x * __bfloat162float(xp[-(ptrdiff_t)(3 * DI)]);
  float s = acc / (1.f + __expf(-acc));   // silu
  xcbf[idx] = __float2bfloat16(s);
}

// ================= chunked selective scan (NCH=64, CHL=32) =================
__global__ __launch_bounds__(64) void scan_part_k(const bf16* __restrict__ delta,
                                                  const float* __restrict__ xdbl,
                                                  const float* __restrict__ A_log,
                                                  float* __restrict__ prodA,
                                                  float* __restrict__ hend) {
  __shared__ float sBC[CHL * 32];
  const int t = threadIdx.x;
  const int dg = blockIdx.x % (DI / 64);
  const int chunk = (blockIdx.x / (DI / 64)) % NCH;
  const int b = blockIdx.x / ((DI / 64) * NCH);
  const int d = dg * 64 + t;

  float a[16];
  #pragma unroll
  for (int s = 0; s < 16; s++) a[s] = -__expf(A_log[s]);

  const float4* src = (const float4*)(xdbl + ((size_t)b * LL + chunk * CHL) * 32);
  #pragma unroll
  for (int k = 0; k < CHL * 32 / 4 / 64; k++) ((float4*)sBC)[t + k * 64] = src[t + k * 64];
  __syncthreads();

  float h[16], p[16];
  #pragma unroll
  for (int s = 0; s < 16; s++) { h[s] = 0.f; p[s] = 1.f; }

  const bf16* dptr = delta + ((size_t)b * LL + chunk * CHL) * DI + d;
  #pragma unroll 2
  for (int i = 0; i < CHL; i++) {
    float dlt = __bfloat162float(dptr[(size_t)i * DI]);
    const float4* bc = (const float4*)(sBC + i * 32);
    float4 B0 = bc[0], B1 = bc[1], B2 = bc[2], B3 = bc[3];
    float Bv[16] = {B0.x,B0.y,B0.z,B0.w, B1.x,B1.y,B1.z,B1.w,
                    B2.x,B2.y,B2.z,B2.w, B3.x,B3.y,B3.z,B3.w};
    #pragma unroll
    for (int s = 0; s < 16; s++) {
      float dA = __expf(dlt * a[s]);
      h[s] = dA * h[s] + dlt * Bv[s];
      p[s] *= dA;
    }
  }
  size_t o = (size_t)chunk * SEQS + ((size_t)b * DI + d) * 16;
  #pragma unroll
  for (int s = 0; s < 16; s += 4) {
    ((float4*)(prodA + o))[s >> 2] = make_float4(p[s], p[s+1], p[s+2], p[s+3]);
    ((float4*)(hend  + o))[s >> 2] = make_float4(h[s], h[s+1], h[s+2], h[s+3]);
  }
}

__global__ __launch_bounds__(64) void scan_comb_k(const float* __restrict__ prodA,
                                                  const float* __restrict__ hend,
                                                  float* __restrict__ hstart) {
  int idx = blockIdx.x * 64 + threadIdx.x;   // 0 .. SEQS-1
  float run = 0.f;
  #pragma unroll 4
  for (int c = 0; c < NCH; c++) {
    size_t o = (size_t)c * SEQS + idx;
    hstart[o] = run;
    run = prodA[o] * run + hend[o];
  }
}

__global__ __launch_bounds__(64) void scan_fin_k(const bf16* __restrict__ delta,
                                                 const float* __restrict__ xdbl,
                                                 const float* __restrict__ A_log,
                                                 const float* __restrict__ Dp,
                                                 const bf16* __restrict__ xcbf,
                                                 const bf16* __restrict__ zbf,
                                                 const float* __restrict__ hstart,
                                                 __hip_bfloat16* __restrict__ ypbf) {
  __shared__ float sBC[CHL * 32];
  const int t = threadIdx.x;
  const int dg = blockIdx.x % (DI / 64);
  const int chunk = (blockIdx.x / (DI / 64)) % NCH;
  const int b = blockIdx.x / ((DI / 64) * NCH);
  const int d = dg * 64 + t;

  float a[16];
  #pragma unroll
  for (int s = 0; s < 16; s++) a[s] = -__expf(A_log[s]);

  const float4* src = (const float4*)(xdbl + ((size_t)b * LL + chunk * CHL) * 32);
  #pragma unroll
  for (int k = 0; k < CHL * 32 / 4 / 64; k++) ((float4*)sBC)[t + k * 64] = src[t + k * 64];
  __syncthreads();

  float h[16];
  size_t o = (size_t)chunk * SEQS + ((size_t)b * DI + d) * 16;
  #pragma unroll
  for (int s = 0; s < 16; s += 4) {
    float4 v = ((const float4*)(hstart + o))[s >> 2];
    h[s] = v.x; h[s+1] = v.y; h[s+2] = v.z; h[s+3] = v.w;
  }
  const float Dv = Dp[d];

  const size_t rbase = (size_t)b * LL + chunk * CHL;
  const bf16* dptr = delta + rbase * DI + d;
  const bf16* xcp  = xcbf  + rbase * DI + d;
  const bf16* zp   = zbf   + rbase * DI + d;
  __hip_bfloat16* yp = ypbf + rbase * DI + d;

  #pragma unroll 2
  for (int i = 0; i < CHL; i++) {
    float dlt = __bfloat162float(dptr[(size_t)i * DI]);
    const float4* bc = (const float4*)(sBC + i * 32);
    float4 B0 = bc[0], B1 = bc[1], B2 = bc[2], B3 = bc[3];
    float4 C0 = bc[4], C1 = bc[5], C2 = bc[6], C3 = bc[7];
    float Bv[16] = {B0.x,B0.y,B0.z,B0.w, B1.x,B1.y,B1.z,B1.w,
                    B2.x,B2.y,B2.z,B2.w, B3.x,B3.y,B3.z,B3.w};
    float Cv[16] = {C0.x,C0.y,C0.z,C0.w, C1.x,C1.y,C1.z,C1.w,
                    C2.x,C2.y,C2.z,C2.w, C3.x,C3.y,C3.z,C3.w};
    float y = 0.f;
    #pragma unroll
    for (int s = 0; s < 16; s++) {
      float dA = __expf(dlt * a[s]);
      h[s] = dA * h[s] + dlt * Bv[s];
      y += h[s] * Cv[s];
    }
    float xcv = __bfloat162float(xcp[(size_t)i * DI]);
    float zv  = __bfloat162float(zp [(size_t)i * DI]);
    float val = (y + Dv * xcv) * (zv / (1.f + __expf(-zv)));
    yp[(size_t)i * DI] = __float2bfloat16(val);
  }
}

extern "C" void kernel_launch(void* const* d_in, const int* in_sizes, int n_in,
                              void* d_out, int out_size, void* d_ws, size_t ws_size,
                              hipStream_t stream) {
  const float* x      = (const float*)d_in[0];
  const float* W_in   = (const float*)d_in[1];
  const float* W_conv = (const float*)d_in[2];
  const float* W_x    = (const float*)d_in[3];
  const float* W_dt   = (const float*)d_in[4];
  const float* b_dt   = (const float*)d_in[5];
  const float* A_log  = (const float*)d_in[6];
  const float* Dp     = (const float*)d_in[7];
  const float* W_out  = (const float*)d_in[8];
  float* out = (float*)d_out;

  char* ws = (char*)d_ws;
  // workspace layout (bytes), max used = 119668736
  bf16*  xpartbf = (bf16*)(ws + 0);          // 12582912 (dead after conv)
  bf16*  zbf     = (bf16*)(ws + 12582912);   // 12582912 (dead after scan_fin)
  bf16*  xbf     = (bf16*)(ws + 25165824);   //  6291456 (dead after GEMM1)
  bf16*  Winbf   = (bf16*)(ws + 31457280);   //  4718592 (dead after GEMM1)
  bf16*  xcbf    = (bf16*)(ws + 36175872);   // 12582912
  bf16*  Wcomb   = (bf16*)(ws + 48758784);   //  5111808
  bf16*  deltabf = (bf16*)(ws + 53870592);   // 12582912
  float* xdbl    = (float*)(ws + 66453504);  //   524288
  bf16*  ypbf    = (bf16*)(ws + 66977792);   // 12582912
  bf16*  Woutbf  = (bf16*)(ws + 79560704);   //  2359296
  float* prodA   = (float*)(ws + 81920000);  // 64*49152*4 = 12582912
  float* hend    = (float*)(ws + 94502912);  // 12582912
  float* hstart  = (float*)(ws + 107085824); // 12582912
  // GEMM3 split-K partials alias [0, 25165824) (xpartbf+zbf, both dead by then):
  float* P3      = (float*)(ws + 0);         // 2 * 4096*768*4 = 25165824

  // merged prep: bf16 converts + Wcomb build
  prep_k<<<(PRTOT + 255) / 256, 256, 0, stream>>>(x, W_in, W_out, W_dt, W_x,
                                                  xbf, Winbf, Woutbf, Wcomb);

  // xz = x @ W_in.T (4096 x 3072, K=768), split bf16 stores into xpartbf | zbf
  {
    dim3 g(3072 / 128, 4096 / 128, 1);   // 768 blocks (%8==0 for swizzle)
    gemm_db<5, 128><<<g, 256, 0, stream>>>(xbf, Winbf, xpartbf, zbf, nullptr,
                                           MM, 2 * DI, DM, DM);
  }
  // xc = silu(causal_dwconv(xpart)), bf16
  conv_silu_k<<<(MM * DI + 255) / 256, 256, 0, stream>>>(xpartbf, W_conv, xcbf);
  // delta = bf16(softplus(xc @ W_dt.T + b_dt)) AND xdbl = xc @ W_x.T (fp32)
  {
    dim3 g(NC2 / 128, 4096 / 128, 1);    // 416 blocks (%8==0 for swizzle)
    gemm_db<6, 128><<<g, 256, 0, stream>>>(xcbf, Wcomb, deltabf, xdbl, b_dt,
                                           MM, NC2, DI, DI);
  }
  // chunked selective scan + gating (NCH=64 -> 3072 blocks, 12 waves/CU)
  scan_part_k<<<BB * NCH * (DI / 64), 64, 0, stream>>>(deltabf, xdbl, A_log, prodA, hend);
  scan_comb_k<<<SEQS / 64, 64, 0, stream>>>(prodA, hend, hstart);
  scan_fin_k<<<BB * NCH * (DI / 64), 64, 0, stream>>>(deltabf, xdbl, A_log, Dp, xcbf, zbf,
                                                      hstart, ypbf);
  // out = y @ W_out.T (4096 x 768, K=1536): split-K=2, partials + reduce
  {
    dim3 g(768 / 128, 4096 / 128, 2);    // 768 blocks (%8==0 for swizzle)
    gemm_db<7, 128><<<g, 256, 0, stream>>>(ypbf, Woutbf, P3, nullptr, nullptr,
                                           MM, DM, DI / 2, DI);
  }
  redk_k<<<(786432 + 255) / 256, 256, 0, stream>>>((const float4*)P3, (float4*)out, 786432);
}